// Round 7
// baseline (107.120 us; speedup 1.0000x reference)
//
#include <hip/hip_runtime.h>
#include <math.h>

#define Bn 64
#define Pn 8732
#define Cn 21
#define NMAXn 50
#define PX 35  // ceil(Pn/256)
#define Wn 16  // waves in a 1024-thread block

// ---------------------------------------------------------------------------
// K0: precompute corner-form priors and areas (read many times afterwards).
// ---------------------------------------------------------------------------
__global__ __launch_bounds__(256) void k_prep(const float* __restrict__ priors,
                                              float4* __restrict__ pc4,
                                              float* __restrict__ pa) {
    const int p = blockIdx.x * 256 + threadIdx.x;
    if (p >= Pn) return;
    const float4 pr = reinterpret_cast<const float4*>(priors)[p];
    const float x0 = pr.x - 0.5f * pr.z, y0 = pr.y - 0.5f * pr.w;
    const float x1 = pr.x + 0.5f * pr.z, y1 = pr.y + 0.5f * pr.w;
    pc4[p] = make_float4(x0, y0, x1, y1);
    pa[p] = (x1 - x0) * (y1 - y0);
}

// ---------------------------------------------------------------------------
// K1: both argmax directions, no LDS-pipe hot loops, no shfl cascades.
// Phase A (thread-per-prior): best GT per p; GT boxes via uniform-address
// global reads (scalar s_load path). Writes match word (idx<<1 | iou>=.5).
// Phase B (lane-per-GT): wave scans its 64-prior slice with wave-uniform
// prior reads (scalar path); per-lane tracker; 4-wave LDS combine; wave 0
// publishes per-GT winner via u64 atomicMax (key = iou_bits<<32 | ~p:
// max => first-max semantics via min-p tie-break). Deterministic.
// ---------------------------------------------------------------------------
__global__ __launch_bounds__(256) void k_bpp(const float* __restrict__ labels,
                                             const int* __restrict__ objc,
                                             const float4* __restrict__ pc4,
                                             const float* __restrict__ pa,
                                             int* __restrict__ match,
                                             unsigned long long* __restrict__ slot) {
    const int b = blockIdx.y;
    const int px = blockIdx.x;
    const int tid = threadIdx.x;
    const int lane = tid & 63, wid = tid >> 6;
    const int cnt = objc[b];                       // uniform -> scalar
    const float* lb = labels + b * NMAXn * 5;      // uniform base

    // ---- phase A: best GT for this thread's prior ----
    const int p = px * 256 + tid;
    const int pcl = (p < Pn) ? p : (Pn - 1);
    const float4 c = pc4[pcl];
    const float myarea = pa[pcl];
    float best = -1.0f;
    int bidx = 0;
    for (int n = 0; n < cnt; ++n) {
        const float gx0 = lb[n * 5 + 0], gy0 = lb[n * 5 + 1];   // uniform -> s_load
        const float gx1 = lb[n * 5 + 2], gy1 = lb[n * 5 + 3];
        const float lx = fmaxf(gx0, c.x), ly = fmaxf(gy0, c.y);
        const float rx = fminf(gx1, c.z), ry = fminf(gy1, c.w);
        const float w = fmaxf(rx - lx, 0.0f), h = fmaxf(ry - ly, 0.0f);
        const float inter = w * h;
        const float ga = (gx1 - gx0) * (gy1 - gy0);
        const float v = inter / (ga + myarea - inter);
        if (v > best) { best = v; bidx = n; }  // strict >: first-occurrence argmax
    }
    if (p < Pn) match[(size_t)b * Pn + p] = (bidx << 1) | (best >= 0.5f ? 1 : 0);

    // ---- phase B: best prior per GT (lane = GT) over this wave's 64 priors ----
    __shared__ float sv[4][64];
    __shared__ int sp[4][64];
    float gx0 = 0.f, gy0 = 0.f, gx1 = 0.f, gy1 = 0.f, ga = 0.f;
    if (lane < cnt) {
        gx0 = lb[lane * 5 + 0]; gy0 = lb[lane * 5 + 1];
        gx1 = lb[lane * 5 + 2]; gy1 = lb[lane * 5 + 3];
        ga = (gx1 - gx0) * (gy1 - gy0);
    }
    float bv = -1.0f;
    int bp_ = 0;
    const int q0 = px * 256 + 64 * wid;
    for (int j = 0; j < 64; ++j) {
        const int q = q0 + j;
        if (q >= Pn) break;                 // wave-uniform
        const float4 pcq = pc4[q];          // wave-uniform -> s_load
        const float paq = pa[q];
        const float lx = fmaxf(gx0, pcq.x), ly = fmaxf(gy0, pcq.y);
        const float rx = fminf(gx1, pcq.z), ry = fminf(gy1, pcq.w);
        const float w = fmaxf(rx - lx, 0.0f), h = fmaxf(ry - ly, 0.0f);
        const float inter = w * h;
        const float v = inter / (ga + paq - inter);
        if (v > bv) { bv = v; bp_ = q; }    // ascending q: strict > keeps min p
    }
    sv[wid][lane] = bv;
    sp[wid][lane] = bp_;
    __syncthreads();
    if (tid < 64 && tid < cnt) {
        float v = sv[0][tid];
        int q = sp[0][tid];
#pragma unroll
        for (int w = 1; w < 4; ++w) {       // ascending wave = ascending q range
            const float ov = sv[w][tid];
            const int oq = sp[w][tid];
            if (ov > v || (ov == v && oq < q)) { v = ov; q = oq; }
        }
        const unsigned long long key =
            ((unsigned long long)__float_as_uint(v) << 32) |
            (unsigned long long)(0xFFFFFFFFu - (unsigned)q);
        atomicMax(&slot[b * NMAXn + tid], key);
    }
}

// ---------------------------------------------------------------------------
// K2: decode per-GT winners and apply forced overrides to match[] serially
// (last n wins == reference scatter order). Block 0 resets the done counter.
// ---------------------------------------------------------------------------
__global__ __launch_bounds__(64) void k_bpr(const int* __restrict__ objc,
                                            const unsigned long long* __restrict__ slot,
                                            int* __restrict__ match,
                                            int* __restrict__ done) {
    __shared__ int sbp[NMAXn];
    const int b = blockIdx.x;
    const int tid = threadIdx.x;
    if (b == 0 && tid == 0) *done = 0;
    const int cnt = objc[b];
    if (tid < cnt) {
        const unsigned long long key = slot[b * NMAXn + tid];
        sbp[tid] = (int)(0xFFFFFFFFu - (unsigned)(key & 0xFFFFFFFFull));
    }
    __syncthreads();
    if (tid == 0) {
        const size_t base = (size_t)b * Pn;
        for (int n = 0; n < cnt; ++n) match[base + sbp[n]] = (n << 1) | 1;
    }
}

// ---------------------------------------------------------------------------
// K3: streaming main pass. Reads match word; lse over 21 logits from an LDS-
// staged conf tile; nll; fused smooth-L1 encode for positives; pos-masked
// mining score lc; per-block partials via plain stores.
// ---------------------------------------------------------------------------
__global__ __launch_bounds__(256) void k_main(const float* __restrict__ conf,
                                              const float* __restrict__ loc,
                                              const float* __restrict__ priors,
                                              const float* __restrict__ labels,
                                              const int* __restrict__ match,
                                              float* __restrict__ lc,
                                              float* __restrict__ part_loc,
                                              float* __restrict__ part_nll,
                                              int* __restrict__ part_np) {
    const int b = blockIdx.y;
    const int px = blockIdx.x;
    const int p0 = px * 256;
    const int tid = threadIdx.x;
    const int rows = min(256, Pn - p0);
    const int p = p0 + ((tid < rows) ? tid : 0);
    const size_t gi = (size_t)b * Pn + p;
    const int w = match[gi];  // issue before staging; latency hides under it

    __shared__ float sconf[256 * Cn];
    __shared__ float lab[NMAXn * 5];
    const float4* src = reinterpret_cast<const float4*>(conf + ((size_t)b * Pn + p0) * Cn);
    const int n4 = rows * Cn / 4;  // rows*21 divisible by 4 for rows in {256,28}
    for (int i = tid; i < n4; i += 256) reinterpret_cast<float4*>(sconf)[i] = src[i];
    for (int i = tid; i < NMAXn * 5; i += 256) lab[i] = labels[b * NMAXn * 5 + i];
    __syncthreads();

    float my_loc = 0.0f, my_nll = 0.0f;
    int my_np = 0;
    if (tid < rows) {
        const int ti = w >> 1;
        const int ct = (w & 1) ? ((int)lab[ti * 5 + 4] + 1) : 0;
        const float* row = sconf + tid * Cn;  // stride 21: odd -> conflict-benign
        float m = row[0];
#pragma unroll
        for (int j = 1; j < Cn; ++j) m = fmaxf(m, row[j]);
        float s2 = 0.0f;
#pragma unroll
        for (int j = 0; j < Cn; ++j) s2 += __expf(row[j] - m);
        const float nll = __logf(s2) + m - row[ct];
        if (ct > 0) {
            lc[gi] = 0.0f;
            my_np = 1;
            my_nll = nll;
            const float4 pr = reinterpret_cast<const float4*>(priors)[p];
            const float gx0 = lab[ti * 5 + 0], gy0 = lab[ti * 5 + 1];
            const float gx1 = lab[ti * 5 + 2], gy1 = lab[ti * 5 + 3];
            const float tx = ((gx0 + gx1) * 0.5f - pr.x) / (0.1f * pr.z);
            const float ty = ((gy0 + gy1) * 0.5f - pr.y) / (0.1f * pr.w);
            const float tw = __logf((gx1 - gx0) / pr.z) * 5.0f;  // /0.2
            const float th = __logf((gy1 - gy0) / pr.w) * 5.0f;
            const float4 l = reinterpret_cast<const float4*>(loc)[gi];
            float d;
            d = fabsf(l.x - tx); my_loc += (d < 1.0f) ? 0.5f * d * d : d - 0.5f;
            d = fabsf(l.y - ty); my_loc += (d < 1.0f) ? 0.5f * d * d : d - 0.5f;
            d = fabsf(l.z - tw); my_loc += (d < 1.0f) ? 0.5f * d * d : d - 0.5f;
            d = fabsf(l.w - th); my_loc += (d < 1.0f) ? 0.5f * d * d : d - 0.5f;
        } else {
            lc[gi] = nll;
        }
    }
    for (int off = 32; off > 0; off >>= 1) {
        my_loc += __shfl_down(my_loc, off);
        my_nll += __shfl_down(my_nll, off);
        my_np += __shfl_down(my_np, off);
    }
    __shared__ float rl[4], rn[4];
    __shared__ int rp[4];
    const int wid = tid >> 6, lane = tid & 63;
    if (lane == 0) { rl[wid] = my_loc; rn[wid] = my_nll; rp[wid] = my_np; }
    __syncthreads();
    if (tid == 0) {
        const int g = b * PX + px;
        part_loc[g] = rl[0] + rl[1] + rl[2] + rl[3];
        part_nll[g] = rn[0] + rn[1] + rn[2] + rn[3];
        part_np[g] = rp[0] + rp[1] + rp[2] + rp[3];
    }
}

// ---------------------------------------------------------------------------
// K4: per-batch hard-negative top-k sum. 1024 threads; scores in registers
// (3 float4/thread, sentinel -1); 31-iter bisection on float bits (exact);
// fused final reduce via done counter.
// ---------------------------------------------------------------------------
__global__ __launch_bounds__(1024) void k_neg(const float* __restrict__ lc,
                                              const float* __restrict__ part_loc,
                                              const float* __restrict__ part_nll,
                                              const int* __restrict__ part_np,
                                              float* __restrict__ negsum,
                                              int* __restrict__ done,
                                              float* __restrict__ out) {
    const int b = blockIdx.x;
    const int tid = threadIdx.x;
    const int lane = tid & 63, wid = tid >> 6;
    __shared__ int redc[2][Wn];
    __shared__ float redf[Wn], redf2[Wn];
    __shared__ int redi[Wn];
    __shared__ int np_sh, islast;

    const int NV = Pn / 4;  // 2183 float4s exactly
    const float4* src = reinterpret_cast<const float4*>(lc + (size_t)b * Pn);
    const float4 sent = make_float4(-1.0f, -1.0f, -1.0f, -1.0f);
    float4 r0 = (tid < NV) ? src[tid] : sent;
    float4 r1 = (tid + 1024 < NV) ? src[tid + 1024] : sent;
    float4 r2 = (tid + 2048 < NV) ? src[tid + 2048] : sent;

    if (tid < 64) {
        int npl = (tid < PX) ? part_np[b * PX + tid] : 0;
        for (int off = 32; off > 0; off >>= 1) npl += __shfl_down(npl, off);
        if (tid == 0) np_sh = npl;
    }
    __syncthreads();
    const int k = min(3 * np_sh, Pn - 1);

    unsigned lo = 0u, hi = 0x7F800000u;
#pragma unroll 1
    for (int it = 0; it < 31; ++it) {
        const unsigned mid = lo + ((hi - lo) >> 1);
        const float fm = __uint_as_float(mid);  // fm >= 0: sentinels never counted
        int c = (r0.x >= fm) + (r0.y >= fm) + (r0.z >= fm) + (r0.w >= fm)
              + (r1.x >= fm) + (r1.y >= fm) + (r1.z >= fm) + (r1.w >= fm)
              + (r2.x >= fm) + (r2.y >= fm) + (r2.z >= fm) + (r2.w >= fm);
        for (int off = 32; off > 0; off >>= 1) c += __shfl_down(c, off);
        if (lane == 0) redc[it & 1][wid] = c;
        __syncthreads();
        int tot = 0;
#pragma unroll
        for (int w = 0; w < Wn; ++w) tot += redc[it & 1][w];
        if (tot >= k) lo = mid;
        else hi = mid;
    }
    const float v = __uint_as_float(lo);  // exact k-th largest value

    float sm = 0.0f;
    int c = 0;
    if (r0.x > v) { sm += r0.x; ++c; }
    if (r0.y > v) { sm += r0.y; ++c; }
    if (r0.z > v) { sm += r0.z; ++c; }
    if (r0.w > v) { sm += r0.w; ++c; }
    if (r1.x > v) { sm += r1.x; ++c; }
    if (r1.y > v) { sm += r1.y; ++c; }
    if (r1.z > v) { sm += r1.z; ++c; }
    if (r1.w > v) { sm += r1.w; ++c; }
    if (r2.x > v) { sm += r2.x; ++c; }
    if (r2.y > v) { sm += r2.y; ++c; }
    if (r2.z > v) { sm += r2.z; ++c; }
    if (r2.w > v) { sm += r2.w; ++c; }
    for (int off = 32; off > 0; off >>= 1) {
        sm += __shfl_down(sm, off);
        c += __shfl_down(c, off);
    }
    if (lane == 0) { redf[wid] = sm; redi[wid] = c; }
    __syncthreads();
    if (tid == 0) {
        float st = 0.0f;
        int ct = 0;
#pragma unroll
        for (int w = 0; w < Wn; ++w) { st += redf[w]; ct += redi[w]; }
        negsum[b] = st + (float)(k - ct) * v;  // exact tie handling at boundary
        __threadfence();
        islast = (atomicAdd(done, 1) == Bn - 1) ? 1 : 0;
    }
    __syncthreads();
    if (!islast) return;
    __threadfence();

    float sl = 0.0f, sn = 0.0f;
    int np = 0;
    for (int i = tid; i < Bn * PX; i += 1024) {
        sl += part_loc[i];
        sn += part_nll[i];
        np += part_np[i];
    }
    if (tid < Bn) sn += negsum[tid];
    for (int off = 32; off > 0; off >>= 1) {
        sl += __shfl_down(sl, off);
        sn += __shfl_down(sn, off);
        np += __shfl_down(np, off);
    }
    if (lane == 0) { redf[wid] = sn; redf2[wid] = sl; redi[wid] = np; }
    __syncthreads();
    if (tid == 0) {
        float tsl = 0.0f, tsn = 0.0f;
        int tnp = 0;
#pragma unroll
        for (int w = 0; w < Wn; ++w) { tsl += redf2[w]; tsn += redf[w]; tnp += redi[w]; }
        const float fN = (float)tnp;
        out[0] = tsl / fN;
        out[1] = tsn / fN;
    }
}

extern "C" void kernel_launch(void* const* d_in, const int* in_sizes, int n_in,
                              void* d_out, int out_size, void* d_ws, size_t ws_size,
                              hipStream_t stream) {
    const float* conf = (const float*)d_in[0];
    const float* loc = (const float*)d_in[1];
    const float* priors = (const float*)d_in[2];
    const float* labels = (const float*)d_in[3];
    const int* objc = (const int*)d_in[4];
    float* out = (float*)d_out;

    // ws layout (bytes, 16B-aligned sections):
    // slot[3200] u64 | pc4[Pn] float4 | pa[Pn] | part_loc/nll/np[2240 each] |
    // negsum[64] | match[Bn*Pn] | lc[Bn*Pn] | done
    unsigned long long* slot = (unsigned long long*)d_ws;               // 25600 B
    float4* pc4 = (float4*)((char*)d_ws + 25600);                       // 139712 B
    float* pa = (float*)((char*)pc4 + Pn * 16);
    float* part_loc = pa + Pn;
    float* part_nll = part_loc + Bn * PX;
    int* part_np = (int*)(part_nll + Bn * PX);
    float* negsum = (float*)(part_np + Bn * PX);
    int* match = (int*)(negsum + Bn);
    float* lc = (float*)(match + (size_t)Bn * Pn);
    int* done = (int*)(lc + (size_t)Bn * Pn);

    hipMemsetAsync(slot, 0, Bn * NMAXn * sizeof(unsigned long long), stream);

    dim3 g(PX, Bn);
    k_prep<<<PX, 256, 0, stream>>>(priors, pc4, pa);
    k_bpp<<<g, 256, 0, stream>>>(labels, objc, pc4, pa, match, slot);
    k_bpr<<<Bn, 64, 0, stream>>>(objc, slot, match, done);
    k_main<<<g, 256, 0, stream>>>(conf, loc, priors, labels, match, lc,
                                  part_loc, part_nll, part_np);
    k_neg<<<Bn, 1024, 0, stream>>>(lc, part_loc, part_nll, part_np, negsum, done, out);
}

// Round 8
// 81.371 us; speedup vs baseline: 1.3164x; 1.3164x over previous
//
#include <hip/hip_runtime.h>
#include <math.h>

#define Bn 64
#define Pn 8732
#define Cn 21
#define NMAXn 50
#define PX 35  // ceil(Pn/256)
#define Wn 16  // waves in a 1024-thread block

// ---------------------------------------------------------------------------
// K1: ONE IoU evaluation per (b,p,n), serving BOTH argmax directions.
// Phase A (thread-per-prior): exact IEEE quotient per GT; track best-over-n
// (strict >, first occurrence); store q into LDS matrix qm[n][tid]; write
// match word (idx<<1 | q>=0.5). Phase B (4 threads per GT): scan qm columns
// from LDS, quad shfl combine (tie -> min p), publish per-GT winner via u64
// atomicMax slot (key = q_bits<<32 | ~p  => first-global-max semantics).
// All comparisons on rounded f32 quotients == reference bitwise.
// ---------------------------------------------------------------------------
__global__ __launch_bounds__(256) void k_bpp(const float* __restrict__ labels,
                                             const int* __restrict__ objc,
                                             const float* __restrict__ priors,
                                             int* __restrict__ match,
                                             unsigned long long* __restrict__ slot) {
    const int b = blockIdx.y;
    const int px = blockIdx.x;
    const int tid = threadIdx.x;
    __shared__ float4 lab4[NMAXn];     // GT corner boxes
    __shared__ float gaa[NMAXn];       // GT areas
    __shared__ float qm[NMAXn][257];   // quotient matrix, padded pitch (51.4 KB)
    __shared__ int cnt_s;
    if (tid == 0) cnt_s = objc[b];
    __syncthreads();
    const int cnt = cnt_s;
    if (tid < cnt) {
        const float* lb = labels + (b * NMAXn + tid) * 5;
        const float x0 = lb[0], y0 = lb[1], x1 = lb[2], y1 = lb[3];
        lab4[tid] = make_float4(x0, y0, x1, y1);
        gaa[tid] = (x1 - x0) * (y1 - y0);
    }
    __syncthreads();

    // ---- phase A ----
    const int p = px * 256 + tid;
    const bool valid = p < Pn;
    const int pcl = valid ? p : (Pn - 1);
    const float4 pr = reinterpret_cast<const float4*>(priors)[pcl];
    const float px0 = pr.x - 0.5f * pr.z, py0 = pr.y - 0.5f * pr.w;
    const float px1 = pr.x + 0.5f * pr.z, py1 = pr.y + 0.5f * pr.w;
    const float parea = (px1 - px0) * (py1 - py0);
    float best = -1.0f;
    int bidx = 0;
    for (int n = 0; n < cnt; ++n) {
        const float4 g = lab4[n];
        const float ga = gaa[n];
        const float lx = fmaxf(g.x, px0), ly = fmaxf(g.y, py0);
        const float rx = fminf(g.z, px1), ry = fminf(g.w, py1);
        const float w = fmaxf(rx - lx, 0.0f), h = fmaxf(ry - ly, 0.0f);
        const float inter = w * h;
        float q = inter / (ga + parea - inter);  // exact IEEE, == reference
        if (!valid) q = -2.0f;                   // dead column: never selected
        qm[n][tid] = q;
        if (q > best) { best = q; bidx = n; }    // strict >: first-occurrence argmax
    }
    if (valid) match[(size_t)b * Pn + p] = (bidx << 1) | (best >= 0.5f ? 1 : 0);
    __syncthreads();

    // ---- phase B: n = tid>>2, sub = tid&3; each scans 64 columns ----
    const int n = tid >> 2, sub = tid & 3;
    if (n < cnt) {
        const int base = sub * 64;
        float bq = -3.0f;
        int bj = base;
        for (int j = 0; j < 64; ++j) {
            const float q = qm[n][base + j];     // 16 banks x 4 lanes: 1.58x, ok
            if (q > bq) { bq = q; bj = base + j; }  // ascending j: first max
        }
#pragma unroll
        for (int off = 2; off > 0; off >>= 1) {  // quad combine (subs ascending)
            const float oq = __shfl_down(bq, off);
            const int oj = __shfl_down(bj, off);
            if (oq > bq || (oq == bq && oj < bj)) { bq = oq; bj = oj; }
        }
        if (sub == 0) {
            const unsigned gp = (unsigned)(px * 256 + bj);
            const unsigned long long key =
                ((unsigned long long)__float_as_uint(bq) << 32) |
                (unsigned long long)(0xFFFFFFFFu - gp);
            atomicMax(&slot[b * NMAXn + n], key);
        }
    }
}

// ---------------------------------------------------------------------------
// K2: decode per-GT winners; forced overrides into match[] with parallel
// last-n-wins (thread n writes iff no later n' maps to the same prior).
// Block 0 resets the done counter for K4.
// ---------------------------------------------------------------------------
__global__ __launch_bounds__(64) void k_bpr(const int* __restrict__ objc,
                                            const unsigned long long* __restrict__ slot,
                                            int* __restrict__ match,
                                            int* __restrict__ done) {
    __shared__ int sbp[NMAXn];
    const int b = blockIdx.x;
    const int tid = threadIdx.x;
    if (b == 0 && tid == 0) *done = 0;
    const int cnt = objc[b];
    if (tid < cnt) {
        const unsigned long long key = slot[b * NMAXn + tid];
        sbp[tid] = (int)(0xFFFFFFFFu - (unsigned)(key & 0xFFFFFFFFull));
    }
    __syncthreads();
    if (tid < cnt) {
        const int myp = sbp[tid];
        bool win = true;
        for (int n2 = tid + 1; n2 < cnt; ++n2) win = win && (sbp[n2] != myp);
        if (win) match[(size_t)b * Pn + myp] = (tid << 1) | 1;
    }
}

// ---------------------------------------------------------------------------
// K3: streaming main pass. Reads match word; lse over 21 logits from LDS-
// staged conf tile; nll; fused smooth-L1 encode for positives; pos-masked
// mining score lc; per-block partials via plain stores.
// ---------------------------------------------------------------------------
__global__ __launch_bounds__(256) void k_main(const float* __restrict__ conf,
                                              const float* __restrict__ loc,
                                              const float* __restrict__ priors,
                                              const float* __restrict__ labels,
                                              const int* __restrict__ match,
                                              float* __restrict__ lc,
                                              float* __restrict__ part_loc,
                                              float* __restrict__ part_nll,
                                              int* __restrict__ part_np) {
    const int b = blockIdx.y;
    const int px = blockIdx.x;
    const int p0 = px * 256;
    const int tid = threadIdx.x;
    const int rows = min(256, Pn - p0);
    const int p = p0 + ((tid < rows) ? tid : 0);
    const size_t gi = (size_t)b * Pn + p;
    const int w = match[gi];  // issue before staging; latency hides under it

    __shared__ float sconf[256 * Cn];
    __shared__ float lab[NMAXn * 5];
    const float4* src = reinterpret_cast<const float4*>(conf + ((size_t)b * Pn + p0) * Cn);
    const int n4 = rows * Cn / 4;  // rows*21 divisible by 4 for rows in {256,28}
    for (int i = tid; i < n4; i += 256) reinterpret_cast<float4*>(sconf)[i] = src[i];
    for (int i = tid; i < NMAXn * 5; i += 256) lab[i] = labels[b * NMAXn * 5 + i];
    __syncthreads();

    float my_loc = 0.0f, my_nll = 0.0f;
    int my_np = 0;
    if (tid < rows) {
        const int ti = w >> 1;
        const int ct = (w & 1) ? ((int)lab[ti * 5 + 4] + 1) : 0;
        const float* row = sconf + tid * Cn;  // stride 21: odd -> conflict-benign
        float m = row[0];
#pragma unroll
        for (int j = 1; j < Cn; ++j) m = fmaxf(m, row[j]);
        float s2 = 0.0f;
#pragma unroll
        for (int j = 0; j < Cn; ++j) s2 += __expf(row[j] - m);
        const float nll = __logf(s2) + m - row[ct];
        if (ct > 0) {
            lc[gi] = 0.0f;
            my_np = 1;
            my_nll = nll;
            const float4 pr = reinterpret_cast<const float4*>(priors)[p];
            const float gx0 = lab[ti * 5 + 0], gy0 = lab[ti * 5 + 1];
            const float gx1 = lab[ti * 5 + 2], gy1 = lab[ti * 5 + 3];
            const float tx = ((gx0 + gx1) * 0.5f - pr.x) / (0.1f * pr.z);
            const float ty = ((gy0 + gy1) * 0.5f - pr.y) / (0.1f * pr.w);
            const float tw = __logf((gx1 - gx0) / pr.z) * 5.0f;  // /0.2
            const float th = __logf((gy1 - gy0) / pr.w) * 5.0f;
            const float4 l = reinterpret_cast<const float4*>(loc)[gi];
            float d;
            d = fabsf(l.x - tx); my_loc += (d < 1.0f) ? 0.5f * d * d : d - 0.5f;
            d = fabsf(l.y - ty); my_loc += (d < 1.0f) ? 0.5f * d * d : d - 0.5f;
            d = fabsf(l.z - tw); my_loc += (d < 1.0f) ? 0.5f * d * d : d - 0.5f;
            d = fabsf(l.w - th); my_loc += (d < 1.0f) ? 0.5f * d * d : d - 0.5f;
        } else {
            lc[gi] = nll;
        }
    }
    for (int off = 32; off > 0; off >>= 1) {
        my_loc += __shfl_down(my_loc, off);
        my_nll += __shfl_down(my_nll, off);
        my_np += __shfl_down(my_np, off);
    }
    __shared__ float rl[4], rn[4];
    __shared__ int rp[4];
    const int wid = tid >> 6, lane = tid & 63;
    if (lane == 0) { rl[wid] = my_loc; rn[wid] = my_nll; rp[wid] = my_np; }
    __syncthreads();
    if (tid == 0) {
        const int g = b * PX + px;
        part_loc[g] = rl[0] + rl[1] + rl[2] + rl[3];
        part_nll[g] = rn[0] + rn[1] + rn[2] + rn[3];
        part_np[g] = rp[0] + rp[1] + rp[2] + rp[3];
    }
}

// ---------------------------------------------------------------------------
// K4: per-batch hard-negative top-k sum. 1024 threads; scores in registers
// (3 float4/thread, sentinel -1); 31-iter bisection on float bits (exact);
// fused final reduce via done counter.
// ---------------------------------------------------------------------------
__global__ __launch_bounds__(1024) void k_neg(const float* __restrict__ lc,
                                              const float* __restrict__ part_loc,
                                              const float* __restrict__ part_nll,
                                              const int* __restrict__ part_np,
                                              float* __restrict__ negsum,
                                              int* __restrict__ done,
                                              float* __restrict__ out) {
    const int b = blockIdx.x;
    const int tid = threadIdx.x;
    const int lane = tid & 63, wid = tid >> 6;
    __shared__ int redc[2][Wn];
    __shared__ float redf[Wn], redf2[Wn];
    __shared__ int redi[Wn];
    __shared__ int np_sh, islast;

    const int NV = Pn / 4;  // 2183 float4s exactly
    const float4* src = reinterpret_cast<const float4*>(lc + (size_t)b * Pn);
    const float4 sent = make_float4(-1.0f, -1.0f, -1.0f, -1.0f);
    float4 r0 = (tid < NV) ? src[tid] : sent;
    float4 r1 = (tid + 1024 < NV) ? src[tid + 1024] : sent;
    float4 r2 = (tid + 2048 < NV) ? src[tid + 2048] : sent;

    if (tid < 64) {
        int npl = (tid < PX) ? part_np[b * PX + tid] : 0;
        for (int off = 32; off > 0; off >>= 1) npl += __shfl_down(npl, off);
        if (tid == 0) np_sh = npl;
    }
    __syncthreads();
    const int k = min(3 * np_sh, Pn - 1);

    unsigned lo = 0u, hi = 0x7F800000u;
#pragma unroll 1
    for (int it = 0; it < 31; ++it) {
        const unsigned mid = lo + ((hi - lo) >> 1);
        const float fm = __uint_as_float(mid);  // fm >= 0: sentinels never counted
        int c = (r0.x >= fm) + (r0.y >= fm) + (r0.z >= fm) + (r0.w >= fm)
              + (r1.x >= fm) + (r1.y >= fm) + (r1.z >= fm) + (r1.w >= fm)
              + (r2.x >= fm) + (r2.y >= fm) + (r2.z >= fm) + (r2.w >= fm);
        for (int off = 32; off > 0; off >>= 1) c += __shfl_down(c, off);
        if (lane == 0) redc[it & 1][wid] = c;
        __syncthreads();
        int tot = 0;
#pragma unroll
        for (int w = 0; w < Wn; ++w) tot += redc[it & 1][w];
        if (tot >= k) lo = mid;
        else hi = mid;
    }
    const float v = __uint_as_float(lo);  // exact k-th largest value

    float sm = 0.0f;
    int c = 0;
    if (r0.x > v) { sm += r0.x; ++c; }
    if (r0.y > v) { sm += r0.y; ++c; }
    if (r0.z > v) { sm += r0.z; ++c; }
    if (r0.w > v) { sm += r0.w; ++c; }
    if (r1.x > v) { sm += r1.x; ++c; }
    if (r1.y > v) { sm += r1.y; ++c; }
    if (r1.z > v) { sm += r1.z; ++c; }
    if (r1.w > v) { sm += r1.w; ++c; }
    if (r2.x > v) { sm += r2.x; ++c; }
    if (r2.y > v) { sm += r2.y; ++c; }
    if (r2.z > v) { sm += r2.z; ++c; }
    if (r2.w > v) { sm += r2.w; ++c; }
    for (int off = 32; off > 0; off >>= 1) {
        sm += __shfl_down(sm, off);
        c += __shfl_down(c, off);
    }
    if (lane == 0) { redf[wid] = sm; redi[wid] = c; }
    __syncthreads();
    if (tid == 0) {
        float st = 0.0f;
        int ct = 0;
#pragma unroll
        for (int w = 0; w < Wn; ++w) { st += redf[w]; ct += redi[w]; }
        negsum[b] = st + (float)(k - ct) * v;  // exact tie handling at boundary
        __threadfence();
        islast = (atomicAdd(done, 1) == Bn - 1) ? 1 : 0;
    }
    __syncthreads();
    if (!islast) return;
    __threadfence();

    float sl = 0.0f, sn = 0.0f;
    int np = 0;
    for (int i = tid; i < Bn * PX; i += 1024) {
        sl += part_loc[i];
        sn += part_nll[i];
        np += part_np[i];
    }
    if (tid < Bn) sn += negsum[tid];
    for (int off = 32; off > 0; off >>= 1) {
        sl += __shfl_down(sl, off);
        sn += __shfl_down(sn, off);
        np += __shfl_down(np, off);
    }
    if (lane == 0) { redf[wid] = sn; redf2[wid] = sl; redi[wid] = np; }
    __syncthreads();
    if (tid == 0) {
        float tsl = 0.0f, tsn = 0.0f;
        int tnp = 0;
#pragma unroll
        for (int w = 0; w < Wn; ++w) { tsl += redf2[w]; tsn += redf[w]; tnp += redi[w]; }
        const float fN = (float)tnp;
        out[0] = tsl / fN;
        out[1] = tsn / fN;
    }
}

extern "C" void kernel_launch(void* const* d_in, const int* in_sizes, int n_in,
                              void* d_out, int out_size, void* d_ws, size_t ws_size,
                              hipStream_t stream) {
    const float* conf = (const float*)d_in[0];
    const float* loc = (const float*)d_in[1];
    const float* priors = (const float*)d_in[2];
    const float* labels = (const float*)d_in[3];
    const int* objc = (const int*)d_in[4];
    float* out = (float*)d_out;

    // ws layout: slot[3200] u64 | part_loc/nll/np[2240 each] | negsum[64] |
    //            match[Bn*Pn] | lc[Bn*Pn] | done
    unsigned long long* slot = (unsigned long long*)d_ws;               // 25600 B
    float* part_loc = (float*)((char*)d_ws + 25600);
    float* part_nll = part_loc + Bn * PX;
    int* part_np = (int*)(part_nll + Bn * PX);
    float* negsum = (float*)(part_np + Bn * PX);
    int* match = (int*)(negsum + Bn);
    float* lc = (float*)(match + (size_t)Bn * Pn);
    int* done = (int*)(lc + (size_t)Bn * Pn);

    hipMemsetAsync(slot, 0, Bn * NMAXn * sizeof(unsigned long long), stream);

    dim3 g(PX, Bn);
    k_bpp<<<g, 256, 0, stream>>>(labels, objc, priors, match, slot);
    k_bpr<<<Bn, 64, 0, stream>>>(objc, slot, match, done);
    k_main<<<g, 256, 0, stream>>>(conf, loc, priors, labels, match, lc,
                                  part_loc, part_nll, part_np);
    k_neg<<<Bn, 1024, 0, stream>>>(lc, part_loc, part_nll, part_np, negsum, done, out);
}

// Round 9
// 78.647 us; speedup vs baseline: 1.3620x; 1.0346x over previous
//
#include <hip/hip_runtime.h>
#include <math.h>

#define Bn 64
#define Pn 8732
#define Cn 21
#define NMAXn 50
#define PX 35  // ceil(Pn/256)
#define Wn 16  // waves in a 1024-thread block

// ---------------- DPP wave64 reduces (VALU pipe, not LDS) -------------------
// bound_ctrl=1: invalid source lanes contribute 0 -> requires operands >= 0
// (true everywhere below). Result lands in lane 63.
template <int C>
__device__ __forceinline__ float dppf(float x) {
    return __int_as_float(__builtin_amdgcn_update_dpp(0, __float_as_int(x), C, 0xf, 0xf, true));
}
template <int C>
__device__ __forceinline__ int dppi(int x) {
    return __builtin_amdgcn_update_dpp(0, x, C, 0xf, 0xf, true);
}
__device__ __forceinline__ float wave_max_f(float x) {  // x >= 0
    x = fmaxf(x, dppf<0x111>(x));  // row_shr:1
    x = fmaxf(x, dppf<0x112>(x));  // row_shr:2
    x = fmaxf(x, dppf<0x114>(x));  // row_shr:4
    x = fmaxf(x, dppf<0x118>(x));  // row_shr:8
    x = fmaxf(x, dppf<0x142>(x));  // row_bcast:15
    x = fmaxf(x, dppf<0x143>(x));  // row_bcast:31
    return x;                      // lane 63 = wave max
}
__device__ __forceinline__ float wave_sum_f(float x) {
    x += dppf<0x111>(x); x += dppf<0x112>(x); x += dppf<0x114>(x);
    x += dppf<0x118>(x); x += dppf<0x142>(x); x += dppf<0x143>(x);
    return x;  // lane 63 = wave sum
}
__device__ __forceinline__ int wave_sum_i(int x) {
    x += dppi<0x111>(x); x += dppi<0x112>(x); x += dppi<0x114>(x);
    x += dppi<0x118>(x); x += dppi<0x142>(x); x += dppi<0x143>(x);
    return x;  // lane 63
}

// ---------------------------------------------------------------------------
// K1: phase A (thread-per-prior): best-GT argmax -> match word. Per GT n:
// wave-max of q via DPP, first-max lane via ballot+ffs (exact min-p tie),
// lane 0 stores key (q_bits<<32 | 65535-p) to bpk[b][n][px*4+wid]. ZERO LDS.
// Invalid lanes (p>=Pn) use q=0 with large p -> can never win a tie.
// ---------------------------------------------------------------------------
__global__ __launch_bounds__(256) void k_bpp(const float* __restrict__ labels,
                                             const int* __restrict__ objc,
                                             const float* __restrict__ priors,
                                             int* __restrict__ match,
                                             unsigned long long* __restrict__ bpk) {
    const int b = blockIdx.y;
    const int px = blockIdx.x;
    const int tid = threadIdx.x;
    const int lane = tid & 63, wid = tid >> 6;
    const int cnt = objc[b];                    // uniform -> scalar
    const float* lb = labels + b * NMAXn * 5;   // uniform base -> s_loads in loop

    const int p = px * 256 + tid;
    const bool valid = p < Pn;
    const int pcl = valid ? p : (Pn - 1);
    const float4 pr = reinterpret_cast<const float4*>(priors)[pcl];
    const float px0 = pr.x - 0.5f * pr.z, py0 = pr.y - 0.5f * pr.w;
    const float px1 = pr.x + 0.5f * pr.z, py1 = pr.y + 0.5f * pr.w;
    const float parea = (px1 - px0) * (py1 - py0);

    float best = -1.0f;
    int bidx = 0;
    for (int n = 0; n < cnt; ++n) {
        const float gx0 = lb[n * 5 + 0], gy0 = lb[n * 5 + 1];
        const float gx1 = lb[n * 5 + 2], gy1 = lb[n * 5 + 3];
        const float lx = fmaxf(gx0, px0), ly = fmaxf(gy0, py0);
        const float rx = fminf(gx1, px1), ry = fminf(gy1, py1);
        const float w = fmaxf(rx - lx, 0.0f), h = fmaxf(ry - ly, 0.0f);
        const float inter = w * h;
        const float ga = (gx1 - gx0) * (gy1 - gy0);
        const float q = inter / (ga + parea - inter);  // exact IEEE == reference
        if (q > best) { best = q; bidx = n; }          // strict >: first occurrence
        const float qr = valid ? q : 0.0f;             // reduce domain: >= 0
        const float m = wave_max_f(qr);
        const float s_q = __int_as_float(__builtin_amdgcn_readlane(__float_as_int(m), 63));
        const unsigned long long mask = __ballot(qr == s_q);
        const int first = __ffsll(mask) - 1;           // lowest lane == min p
        if (lane == 0) {
            const int pw = px * 256 + (wid << 6) + first;
            const unsigned long long key =
                ((unsigned long long)__float_as_uint(s_q) << 32) |
                (unsigned long long)(65535 - pw);      // larger key = better (q, then min p)
            bpk[(size_t)(b * NMAXn + n) * (PX * 4) + px * 4 + wid] = key;
        }
    }
    if (valid) match[(size_t)b * Pn + p] = (bidx << 1) | (best >= 0.5f ? 1 : 0);
}

// ---------------------------------------------------------------------------
// K2: per-GT max over the 140 wave keys -> forced prior; overrides into
// match[] with parallel last-n-wins. Resets the done counter.
// ---------------------------------------------------------------------------
__global__ __launch_bounds__(64) void k_bpr(const int* __restrict__ objc,
                                            const unsigned long long* __restrict__ bpk,
                                            int* __restrict__ match,
                                            int* __restrict__ done) {
    __shared__ int sbp[NMAXn];
    const int b = blockIdx.x;
    const int tid = threadIdx.x;
    if (b == 0 && tid == 0) *done = 0;
    const int cnt = objc[b];
    if (tid < cnt) {
        const size_t g0 = (size_t)(b * NMAXn + tid) * (PX * 4);
        unsigned long long best = 0ull;
        for (int t = 0; t < PX * 4; ++t) {
            const unsigned long long k = bpk[g0 + t];
            best = (k > best) ? k : best;
        }
        sbp[tid] = 65535 - (int)(best & 0xFFFFull);
    }
    __syncthreads();
    if (tid < cnt) {
        const int myp = sbp[tid];
        bool win = true;
        for (int n2 = tid + 1; n2 < cnt; ++n2) win = win && (sbp[n2] != myp);
        if (win) match[(size_t)b * Pn + myp] = (tid << 1) | 1;
    }
}

// ---------------------------------------------------------------------------
// K3: streaming main pass, NO LDS staging. 21 logits straight into registers
// (lanes span contiguous 5.4KB -> coalesced lines); target logit via unrolled
// compile-time-index selects; GT/prior data loaded only for positives.
// Block reduce via DPP; partials by plain stores.
// ---------------------------------------------------------------------------
__global__ __launch_bounds__(256) void k_main(const float* __restrict__ conf,
                                              const float* __restrict__ loc,
                                              const float* __restrict__ priors,
                                              const float* __restrict__ labels,
                                              const int* __restrict__ match,
                                              float* __restrict__ lc,
                                              float* __restrict__ part_loc,
                                              float* __restrict__ part_nll,
                                              int* __restrict__ part_np) {
    const int b = blockIdx.y;
    const int px = blockIdx.x;
    const int p0 = px * 256;
    const int tid = threadIdx.x;
    const int rows = min(256, Pn - p0);
    const int p = p0 + ((tid < rows) ? tid : 0);
    const size_t gi = (size_t)b * Pn + p;
    const int w = match[gi];

    const float* row = conf + gi * Cn;
    float a[Cn];
#pragma unroll
    for (int j = 0; j < Cn; ++j) a[j] = row[j];

    float my_loc = 0.0f, my_nll = 0.0f;
    int my_np = 0;
    if (tid < rows) {
        const int ti = w >> 1;
        int ct = 0;
        if (w & 1) ct = (int)labels[(b * NMAXn + ti) * 5 + 4] + 1;  // scattered, L2-hot
        float m = a[0];
#pragma unroll
        for (int j = 1; j < Cn; ++j) m = fmaxf(m, a[j]);
        float s2 = 0.0f;
#pragma unroll
        for (int j = 0; j < Cn; ++j) s2 += __expf(a[j] - m);
        float tgt = a[0];
#pragma unroll
        for (int j = 1; j < Cn; ++j) tgt = (ct == j) ? a[j] : tgt;  // no runtime reg index
        const float nll = __logf(s2) + m - tgt;
        if (ct > 0) {
            lc[gi] = 0.0f;
            my_np = 1;
            my_nll = nll;
            const float* lbp = labels + (b * NMAXn + ti) * 5;
            const float gx0 = lbp[0], gy0 = lbp[1], gx1 = lbp[2], gy1 = lbp[3];
            const float4 pr = reinterpret_cast<const float4*>(priors)[p];
            const float tx = ((gx0 + gx1) * 0.5f - pr.x) / (0.1f * pr.z);
            const float ty = ((gy0 + gy1) * 0.5f - pr.y) / (0.1f * pr.w);
            const float tw = __logf((gx1 - gx0) / pr.z) * 5.0f;  // /0.2
            const float th = __logf((gy1 - gy0) / pr.w) * 5.0f;
            const float4 l = reinterpret_cast<const float4*>(loc)[gi];
            float d;
            d = fabsf(l.x - tx); my_loc += (d < 1.0f) ? 0.5f * d * d : d - 0.5f;
            d = fabsf(l.y - ty); my_loc += (d < 1.0f) ? 0.5f * d * d : d - 0.5f;
            d = fabsf(l.z - tw); my_loc += (d < 1.0f) ? 0.5f * d * d : d - 0.5f;
            d = fabsf(l.w - th); my_loc += (d < 1.0f) ? 0.5f * d * d : d - 0.5f;
        } else {
            lc[gi] = nll;
        }
    }
    my_loc = wave_sum_f(my_loc);
    my_nll = wave_sum_f(my_nll);
    my_np = wave_sum_i(my_np);
    __shared__ float rl[4], rn[4];
    __shared__ int rp[4];
    const int wid = tid >> 6, lane = tid & 63;
    if (lane == 63) { rl[wid] = my_loc; rn[wid] = my_nll; rp[wid] = my_np; }
    __syncthreads();
    if (tid == 0) {
        const int g = b * PX + px;
        part_loc[g] = rl[0] + rl[1] + rl[2] + rl[3];
        part_nll[g] = rn[0] + rn[1] + rn[2] + rn[3];
        part_np[g] = rp[0] + rp[1] + rp[2] + rp[3];
    }
}

// ---------------------------------------------------------------------------
// K4: per-batch hard-negative top-k sum. 1024 threads; scores in registers;
// 31-iter bisection on float bits (exact); all reduces via DPP (VALU pipe);
// fused final reduce via done counter.
// ---------------------------------------------------------------------------
__global__ __launch_bounds__(1024) void k_neg(const float* __restrict__ lc,
                                              const float* __restrict__ part_loc,
                                              const float* __restrict__ part_nll,
                                              const int* __restrict__ part_np,
                                              float* __restrict__ negsum,
                                              int* __restrict__ done,
                                              float* __restrict__ out) {
    const int b = blockIdx.x;
    const int tid = threadIdx.x;
    const int lane = tid & 63, wid = tid >> 6;
    __shared__ int redc[2][Wn];
    __shared__ float redf[Wn], redf2[Wn];
    __shared__ int redi[Wn];
    __shared__ int np_sh, islast;

    const int NV = Pn / 4;  // 2183 float4s exactly
    const float4* src = reinterpret_cast<const float4*>(lc + (size_t)b * Pn);
    const float4 sent = make_float4(-1.0f, -1.0f, -1.0f, -1.0f);
    float4 r0 = (tid < NV) ? src[tid] : sent;
    float4 r1 = (tid + 1024 < NV) ? src[tid + 1024] : sent;
    float4 r2 = (tid + 2048 < NV) ? src[tid + 2048] : sent;

    if (tid < 64) {
        int npl = (tid < PX) ? part_np[b * PX + tid] : 0;
        npl = wave_sum_i(npl);
        if (tid == 63) np_sh = npl;
    }
    __syncthreads();
    const int k = min(3 * np_sh, Pn - 1);

    unsigned lo = 0u, hi = 0x7F800000u;
#pragma unroll 1
    for (int it = 0; it < 31; ++it) {
        const unsigned mid = lo + ((hi - lo) >> 1);
        const float fm = __uint_as_float(mid);  // fm >= 0: sentinels never counted
        int c = (r0.x >= fm) + (r0.y >= fm) + (r0.z >= fm) + (r0.w >= fm)
              + (r1.x >= fm) + (r1.y >= fm) + (r1.z >= fm) + (r1.w >= fm)
              + (r2.x >= fm) + (r2.y >= fm) + (r2.z >= fm) + (r2.w >= fm);
        c = wave_sum_i(c);
        if (lane == 63) redc[it & 1][wid] = c;
        __syncthreads();
        int tot = 0;
#pragma unroll
        for (int w = 0; w < Wn; ++w) tot += redc[it & 1][w];
        if (tot >= k) lo = mid;
        else hi = mid;
    }
    const float v = __uint_as_float(lo);  // exact k-th largest value

    float sm = 0.0f;
    int c = 0;
    if (r0.x > v) { sm += r0.x; ++c; }
    if (r0.y > v) { sm += r0.y; ++c; }
    if (r0.z > v) { sm += r0.z; ++c; }
    if (r0.w > v) { sm += r0.w; ++c; }
    if (r1.x > v) { sm += r1.x; ++c; }
    if (r1.y > v) { sm += r1.y; ++c; }
    if (r1.z > v) { sm += r1.z; ++c; }
    if (r1.w > v) { sm += r1.w; ++c; }
    if (r2.x > v) { sm += r2.x; ++c; }
    if (r2.y > v) { sm += r2.y; ++c; }
    if (r2.z > v) { sm += r2.z; ++c; }
    if (r2.w > v) { sm += r2.w; ++c; }
    sm = wave_sum_f(sm);
    c = wave_sum_i(c);
    if (lane == 63) { redf[wid] = sm; redi[wid] = c; }
    __syncthreads();
    if (tid == 0) {
        float st = 0.0f;
        int ct = 0;
#pragma unroll
        for (int w = 0; w < Wn; ++w) { st += redf[w]; ct += redi[w]; }
        negsum[b] = st + (float)(k - ct) * v;  // exact tie handling at boundary
        __threadfence();
        islast = (atomicAdd(done, 1) == Bn - 1) ? 1 : 0;
    }
    __syncthreads();
    if (!islast) return;
    __threadfence();  // acquire: other blocks' stores precede their fenced atomics

    float sl = 0.0f, sn = 0.0f;
    int np = 0;
    for (int i = tid; i < Bn * PX; i += 1024) {
        sl += part_loc[i];
        sn += part_nll[i];
        np += part_np[i];
    }
    if (tid < Bn) sn += negsum[tid];
    sl = wave_sum_f(sl);
    sn = wave_sum_f(sn);
    np = wave_sum_i(np);
    if (lane == 63) { redf[wid] = sn; redf2[wid] = sl; redi[wid] = np; }
    __syncthreads();
    if (tid == 0) {
        float tsl = 0.0f, tsn = 0.0f;
        int tnp = 0;
#pragma unroll
        for (int w = 0; w < Wn; ++w) { tsl += redf2[w]; tsn += redf[w]; tnp += redi[w]; }
        const float fN = (float)tnp;
        out[0] = tsl / fN;
        out[1] = tsn / fN;
    }
}

extern "C" void kernel_launch(void* const* d_in, const int* in_sizes, int n_in,
                              void* d_out, int out_size, void* d_ws, size_t ws_size,
                              hipStream_t stream) {
    const float* conf = (const float*)d_in[0];
    const float* loc = (const float*)d_in[1];
    const float* priors = (const float*)d_in[2];
    const float* labels = (const float*)d_in[3];
    const int* objc = (const int*)d_in[4];
    float* out = (float*)d_out;

    // ws layout: bpk[Bn*NMAXn*140] u64 | part_loc/nll/np[2240 each] |
    //            negsum[64] | match[Bn*Pn] | lc[Bn*Pn] | done
    unsigned long long* bpk = (unsigned long long*)d_ws;          // 3.584 MB
    float* part_loc = (float*)(bpk + (size_t)Bn * NMAXn * PX * 4);
    float* part_nll = part_loc + Bn * PX;
    int* part_np = (int*)(part_nll + Bn * PX);
    float* negsum = (float*)(part_np + Bn * PX);
    int* match = (int*)(negsum + Bn);
    float* lc = (float*)(match + (size_t)Bn * Pn);
    int* done = (int*)(lc + (size_t)Bn * Pn);

    dim3 g(PX, Bn);
    k_bpp<<<g, 256, 0, stream>>>(labels, objc, priors, match, bpk);
    k_bpr<<<Bn, 64, 0, stream>>>(objc, bpk, match, done);
    k_main<<<g, 256, 0, stream>>>(conf, loc, priors, labels, match, lc,
                                  part_loc, part_nll, part_np);
    k_neg<<<Bn, 1024, 0, stream>>>(lc, part_loc, part_nll, part_np, negsum, done, out);
}